// Round 4
// baseline (1170.440 us; speedup 1.0000x reference)
//
#include <hip/hip_runtime.h>
#include <hip/hip_bf16.h>

// VectorQuantizer2 forward (VAR multi-scale VQ) on MI355X.
// B=512, C=32, H=64, W=1, V=4096 codes, scales pn=1,2,4,8,16,32,64.
// Identities: f_hat + f_rest == f  ->  loss_si = 1.25*mean(f_rest^2), out = f - f_rest_final.
// Conv 3x3 with W=1 + zero pad == 3x1 conv along H with kernel column kw=1.
// phi index per stage (exact fp64 replay of np.linspace ticks, re-derived twice):
//   si=0..6 -> pi=0,0,1,2,2,3,3.  si=3 near-tie resolves DOWN-UP asymmetrically:
//   |0.5-ticks[1]| = 5/36+6.17e-17  >  |ticks[2]-0.5| = 5/36-4.93e-17  => pi=2.
// Argmin robustness: fp32 top-2 scan; fp64 chunk rescan when gap < TAU; fp64 re-score of
// every chunk winner so the cross-chunk reduce is exact (matches float64 numpy ordering).

#define B_ 512
#define C_ 32
#define H_ 64
#define V_ 4096
#define TOT (B_*C_*H_)   // 1048576

__device__ __forceinline__ float cubicw(float d) {
    d = fabsf(d);
    const float d2 = d * d, d3 = d2 * d;
    if (d <= 1.0f) return 1.25f * d3 - 2.25f * d2 + 1.0f;          // a=-0.75
    if (d < 2.0f)  return -0.75f * d3 + 3.75f * d2 - 6.0f * d + 3.0f;
    return 0.0f;
}

__device__ __forceinline__ double dot64(const float4* a, const float* er) {
    double s = 0.0;
#pragma unroll
    for (int k = 0; k < 8; ++k) {
        s += (double)a[k].x * (double)er[4*k+0];
        s += (double)a[k].y * (double)er[4*k+1];
        s += (double)a[k].z * (double)er[4*k+2];
        s += (double)a[k].w * (double)er[4*k+3];
    }
    return s;
}

// ---------------- init: e_sq (f32+f64), compact conv weights, stage-0 pooled rest, zero loss
__global__ __launch_bounds__(256) void vq_init(
    const float* __restrict__ f, const float* __restrict__ emb,
    const float* __restrict__ phi_w,
    float* __restrict__ esqf, double* __restrict__ esqd,
    float* __restrict__ wmidc, float* __restrict__ rest0, float* __restrict__ loss_acc)
{
    const int blk = blockIdx.x, t = threadIdx.x;
    if (blk < 16) {                       // e_sq[4096] in fp64 (exact ordering source)
        const int v = blk * 256 + t;
        const float* er = emb + (long)v * 32;
        double s = 0.0;
#pragma unroll
        for (int k = 0; k < 32; ++k) { const double e = (double)er[k]; s += e * e; }
        esqd[v] = s;
        esqf[v] = (float)s;
    } else if (blk < 20) {                // wmidc[pi][c][cp][kh] = phi_w[pi][c][cp][kh][1]
        const int pi = blk - 16;
        for (int e = t; e < 3072; e += 256) {
            const int c = e / 96, r = e % 96, cp = r / 3, kh = r % 3;
            wmidc[pi * 3072 + e] = phi_w[(long)((pi*32 + c)*32 + cp)*9 + kh*3 + 1];
        }
    } else if (blk < 84) {                // rest0[b][c] = mean_i f[b][c][i]
        const int out = (blk - 20) * 256 + t;
        const int b = out >> 5, c = out & 31;
        const float4* fv = reinterpret_cast<const float4*>(f) + (long)(b*32 + c) * 16;
        float s0=0.f,s1=0.f,s2=0.f,s3=0.f;
#pragma unroll
        for (int k = 0; k < 16; ++k) {
            float4 e = fv[k];
            if ((k&3)==0){s0=s0+e.x+e.y+e.z+e.w;}
            else if((k&3)==1){s1=s1+e.x+e.y+e.z+e.w;}
            else if((k&3)==2){s2=s2+e.x+e.y+e.z+e.w;}
            else {s3=s3+e.x+e.y+e.z+e.w;}
        }
        rest0[out] = ((s0 + s1) + (s2 + s3)) * (1.0f / 64.0f);
    } else {
        if (t == 0) *loss_acc = 0.0f;
    }
}

// ---------------- VQ nearest-code search. 512 rows/block (2 per thread), codes split VSPLIT ways.
template<int PN, int VSPLIT>
__global__ __launch_bounds__(256) void vq_search(
    const float* __restrict__ rest,   // [B*PN][32]
    const float* __restrict__ emb,    // [4096][32]
    const float* __restrict__ esqf,   // [4096]
    const double* __restrict__ esqd,  // [4096]
    double* __restrict__ minv_p,      // [B*PN*VSPLIT]
    int*    __restrict__ mini_p)
{
    constexpr int VC = V_ / VSPLIT;
    const int t = threadIdx.x;
    const long rowbase = (long)blockIdx.x * 512;
    const int vs = blockIdx.y;
    const long r0 = rowbase + t, r1 = rowbase + t + 256;
    const float4* __restrict__ rv = reinterpret_cast<const float4*>(rest);
    const float4* __restrict__ ev = reinterpret_cast<const float4*>(emb);

    float4 a[8], b8[8];
#pragma unroll
    for (int k = 0; k < 8; ++k) { a[k] = rv[r0*8 + k]; b8[k] = rv[r1*8 + k]; }

    const int j0 = vs * VC;
    float m1a = 3.402823466e38f, m2a = 3.402823466e38f;
    float m1b = 3.402823466e38f, m2b = 3.402823466e38f;
    int mia = j0, mib = j0;
#pragma unroll 2
    for (int jj = 0; jj < VC; ++jj) {
        const int j = j0 + jj;               // wave-uniform -> scalar loads
        float4 e[8];
#pragma unroll
        for (int k = 0; k < 8; ++k) e[k] = ev[(long)j*8 + k];
        const float es = esqf[j];
        float pa[4] = {0,0,0,0}, pb[4] = {0,0,0,0};
#pragma unroll
        for (int k = 0; k < 8; ++k) {
            const int s = k & 3;
            pa[s]=fmaf(a[k].x,e[k].x,pa[s]); pa[s]=fmaf(a[k].y,e[k].y,pa[s]);
            pa[s]=fmaf(a[k].z,e[k].z,pa[s]); pa[s]=fmaf(a[k].w,e[k].w,pa[s]);
            pb[s]=fmaf(b8[k].x,e[k].x,pb[s]); pb[s]=fmaf(b8[k].y,e[k].y,pb[s]);
            pb[s]=fmaf(b8[k].z,e[k].z,pb[s]); pb[s]=fmaf(b8[k].w,e[k].w,pb[s]);
        }
        const float sa = fmaf(-2.0f, (pa[0]+pa[1])+(pa[2]+pa[3]), es);  // ||e||^2 - 2 r.e
        const float sb = fmaf(-2.0f, (pb[0]+pb[1])+(pb[2]+pb[3]), es);
        if (sa < m1a) { m2a = m1a; m1a = sa; mia = j; } else if (sa < m2a) m2a = sa;
        if (sb < m1b) { m2b = m1b; m1b = sb; mib = j; } else if (sb < m2b) m2b = sb;
    }

    // Rare path: fp32 gap too small to trust ordering -> exact fp64 rescan of this chunk.
    if (__any((m2a - m1a < 4e-3f) || (m2b - m1b < 4e-3f))) {
        double c1a = 1e300, c1b = 1e300;
        int cia = mia, cib = mib;
        for (int jj = 0; jj < VC; ++jj) {
            const int j = j0 + jj;
            const float* er = emb + (long)j * 32;
            const double da = dot64(a, er), db = dot64(b8, er);
            const double sa = esqd[j] - 2.0 * da;
            const double sb = esqd[j] - 2.0 * db;
            if (sa < c1a) { c1a = sa; cia = j; }
            if (sb < c1b) { c1b = sb; cib = j; }
        }
        mia = cia; mib = cib;
    }

    // Exact fp64 score of each chunk winner -> cross-chunk reduce is exact.
    {
        const float* er = emb + (long)mia * 32;
        minv_p[r0*VSPLIT + vs] = esqd[mia] - 2.0 * dot64(a, er);
        mini_p[r0*VSPLIT + vs] = mia;
    }
    {
        const float* er = emb + (long)mib * 32;
        minv_p[r1*VSPLIT + vs] = esqd[mib] - 2.0 * dot64(b8, er);
        mini_p[r1*VSPLIT + vs] = mib;
    }
}

// ---------------- finalize: reduce argmin, gather, bicubic up, 3x1 conv, residual+loss+next pool
template<int PN, int VS, int PI, int NPN, bool FIRST, bool LAST>
__global__ __launch_bounds__(256) void vq_finalize(
    const float* __restrict__ f,
    const float* __restrict__ emb,
    const double* __restrict__ minv_p,
    const int*    __restrict__ mini_p,
    const float* __restrict__ wmidc,   // [4][32][32][3]
    const float* __restrict__ phi_b,   // [4][32]
    float* __restrict__ f_rest,
    float* __restrict__ rest_next,     // [B*NPN][32]
    float* __restrict__ loss_acc,
    float* __restrict__ f_hat_out)
{
    __shared__ int   idx_s[PN];
    __shared__ float hs[32][65];
    __shared__ float huc[32][68];      // rows i+1 for i in [-1,64]; cols 0 and 65 are zero pad
    __shared__ float wsum[4];
    const int t = threadIdx.x;
    const int b = blockIdx.x;

    if (t < PN) {                      // ascending chunks + strict < => first-index argmin
        const long row = (long)b * PN + t;
        double mv = minv_p[row*VS];
        int   mi = mini_p[row*VS];
#pragma unroll
        for (int v2 = 1; v2 < VS; ++v2) {
            const double mvv = minv_p[row*VS + v2];
            const int    mii = mini_p[row*VS + v2];
            if (mvv < mv) { mv = mvv; mi = mii; }
        }
        idx_s[t] = mi;
    }
    if (t < 32) { huc[t][0] = 0.0f; huc[t][65] = 0.0f; }
    __syncthreads();

    for (int e = t; e < PN*32; e += 256) {   // gather codes: hs[c][p]
        const int c = e & 31, p = e >> 5;
        hs[c][p] = emb[(long)idx_s[p]*32 + c];
    }
    __syncthreads();

    const int i  = t & 63;             // lane = output position along H
    const int wv = t >> 6;             // wave = channel block of 8
    const int c0 = wv * 8;
    if constexpr (PN == 64) {
#pragma unroll
        for (int o = 0; o < 8; ++o) huc[c0+o][i+1] = hs[c0+o][i];
    } else {
        constexpr float scale = (float)PN / 64.0f;
        const float src = ((float)i + 0.5f) * scale - 0.5f;
        const float fi0 = floorf(src);
        const float tt  = src - fi0;
        const int   i0  = (int)fi0;
        const float w0 = cubicw(tt + 1.0f), w1 = cubicw(tt);
        const float w2 = cubicw(1.0f - tt), w3 = cubicw(2.0f - tt);
        const int k0 = min(max(i0 - 1, 0), PN - 1);
        const int k1 = min(max(i0    , 0), PN - 1);
        const int k2 = min(max(i0 + 1, 0), PN - 1);
        const int k3 = min(max(i0 + 2, 0), PN - 1);
#pragma unroll
        for (int o = 0; o < 8; ++o) {
            const int c = c0 + o;
            float v = w0 * hs[c][k0];
            v = fmaf(w1, hs[c][k1], v);
            v = fmaf(w2, hs[c][k2], v);
            v = fmaf(w3, hs[c][k3], v);
            huc[c][i+1] = v;
        }
    }
    __syncthreads();

    // 3x1 conv along H; weights wave-uniform -> scalar loads
    const int c0u = __builtin_amdgcn_readfirstlane(c0);
    const float* __restrict__ wb = wmidc + PI*3072 + c0u*96;
    float acc[8] = {0,0,0,0,0,0,0,0};
#pragma unroll 8
    for (int cp = 0; cp < 32; ++cp) {
        const float x0 = huc[cp][i];
        const float x1 = huc[cp][i+1];
        const float x2 = huc[cp][i+2];
#pragma unroll
        for (int o = 0; o < 8; ++o) {
            const float* w = wb + o*96 + cp*3;
            acc[o] = fmaf(w[0], x0, acc[o]);
            acc[o] = fmaf(w[1], x1, acc[o]);
            acc[o] = fmaf(w[2], x2, acc[o]);
        }
    }

    float sq = 0.0f;
#pragma unroll
    for (int o = 0; o < 8; ++o) {
        const int c = c0 + o;
        const float h  = huc[c][i+1];
        const float hn = 0.5f * h + 0.5f * (acc[o] + phi_b[PI*32 + c0u + o]);
        const long  g  = ((long)(b*32 + c))*64 + i;
        const float fr = (FIRST ? f[g] : f_rest[g]) - hn;
        sq = fmaf(fr, fr, sq);
        if constexpr (!LAST) {
            f_rest[g] = fr;
            constexpr int cs = 64 / NPN;   // pool chunk for next stage
            float v = fr;
            if constexpr (cs > 1) {
#pragma unroll
                for (int off = cs >> 1; off > 0; off >>= 1) v += __shfl_xor(v, off);
            }
            if ((i & (cs - 1)) == 0)
                rest_next[((long)(b*NPN) + i/cs)*32 + c] = v * (1.0f/(float)cs);
        } else {
            f_hat_out[g] = f[g] - fr;      // f_hat = f - f_rest
        }
    }
#pragma unroll
    for (int off = 32; off > 0; off >>= 1) sq += __shfl_xor(sq, off);
    if ((t & 63) == 0) wsum[wv] = sq;
    __syncthreads();
    if (t == 0)
        atomicAdd(loss_acc, ((wsum[0]+wsum[1])+(wsum[2]+wsum[3])) * (1.25f/(7.0f*1048576.0f)));
}

extern "C" void kernel_launch(void* const* d_in, const int* in_sizes, int n_in,
                              void* d_out, int out_size, void* d_ws, size_t ws_size,
                              hipStream_t stream) {
    const float* f     = (const float*)d_in[0];
    const float* emb   = (const float*)d_in[1];
    const float* phi_w = (const float*)d_in[2];
    const float* phi_b = (const float*)d_in[3];
    float* out = (float*)d_out;
    float* ws  = (float*)d_ws;

    // ws layout (float offsets), total 2908160 floats ~= 11.6 MB
    float*  f_rest = ws;                          // 1048576
    float*  rest   = ws + 1048576;                // 1048576
    float*  esqf   = ws + 2097152;                // 4096
    double* esqd   = (double*)(ws + 2101248);     // 4096 doubles (8B-aligned offset)
    float*  wmidc  = ws + 2109440;                // 12288
    double* minvd  = (double*)(ws + 2121728);     // 262144 doubles
    int*    minip  = (int*)(ws + 2646016);        // 262144
    float*  loss_acc = out + TOT;

    vq_init<<<85, 256, 0, stream>>>(f, emb, phi_w, esqf, esqd, wmidc, rest, loss_acc);

    // stage order: pn = 1,2,4,8,16,32,64 ; pi = 0,0,1,2,2,3,3  (si=3 near-tie -> 2, fp64-exact)
#define SEARCH(PN, VS) vq_search<PN, VS><<<dim3((B_*PN)/512, VS), 256, 0, stream>>>( \
        rest, emb, esqf, esqd, minvd, minip)
#define FINAL(PN, VS, PI, NPN, FIRST, LAST) \
    vq_finalize<PN, VS, PI, NPN, FIRST, LAST><<<B_, 256, 0, stream>>>( \
        f, emb, minvd, minip, wmidc, phi_b, f_rest, rest, loss_acc, out)

    SEARCH(1, 128);  FINAL(1, 128, 0, 2,  true,  false);
    SEARCH(2, 128);  FINAL(2, 128, 0, 4,  false, false);
    SEARCH(4, 64);   FINAL(4, 64, 1, 8,  false, false);
    SEARCH(8, 64);   FINAL(8, 64, 2, 16, false, false);
    SEARCH(16, 32);  FINAL(16, 32, 2, 32, false, false);
    SEARCH(32, 16);  FINAL(32, 16, 3, 64, false, false);
    SEARCH(64, 8);   FINAL(64, 8, 3, 64, false, true);
#undef SEARCH
#undef FINAL
}